// Round 1
// baseline (388.403 us; speedup 1.0000x reference)
//
#include <hip/hip_runtime.h>
#include <math.h>

// MoE router: T=16384 tokens, H=4096, E=8 experts, K=2.
// d_out layout (float32, flat, reference return order):
//   [0      , 32768 )  routing_weights  (T,2)
//   [32768  , 65536 )  selected_experts (T,2)  stored as float(index)
//   [65536  , 196608)  router_logits    (T,8)
//   [196608 ]          aux_loss (scalar)
// d_ws: ws[0..7] = sum of probs per expert, ws[8..15] = top1 counts (float).

#define T_TOKENS 16384
#define H_DIM    4096
#define NEXP     8
#define H4       (H_DIM / 4)   // 1024 float4 per row
#define ITERS    (H4 / 64)     // 16 float4 chunks per lane per token
#define TOK_PER_WAVE 4
#define WAVES_PER_BLOCK 4
#define TOK_PER_BLOCK (TOK_PER_WAVE * WAVES_PER_BLOCK)  // 16

#define OFF_RW  0
#define OFF_SE  32768
#define OFF_LG  65536
#define OFF_AUX 196608

// Halving butterfly step: value set of size 2N -> N, summing over lane pairs
// differing in bit OFFSET. After all steps lane l holds full sum of value l>>1.
#define RED_STEP(OFFSET, N)                                        \
  {                                                                \
    const bool hi = (lane & (OFFSET)) != 0;                        \
    _Pragma("unroll")                                              \
    for (int i = 0; i < (N); ++i) {                                \
      float send = hi ? r[i] : r[i + (N)];                         \
      float recv = __shfl_xor(send, (OFFSET), 64);                 \
      r[i] = (hi ? r[i + (N)] : r[i]) + recv;                      \
    }                                                              \
  }

__global__ __launch_bounds__(256, 4)
void router_kernel(const float* __restrict__ hs, const float* __restrict__ gw,
                   float* __restrict__ out, float* __restrict__ ws) {
  __shared__ float smP[NEXP];
  __shared__ float smC[NEXP];
  if (threadIdx.x < NEXP) { smP[threadIdx.x] = 0.f; smC[threadIdx.x] = 0.f; }
  __syncthreads();

  const int lane = threadIdx.x & 63;
  const int wave = threadIdx.x >> 6;
  const int tokenBase = (blockIdx.x * WAVES_PER_BLOCK + wave) * TOK_PER_WAVE;

  const float4* __restrict__ h4p = reinterpret_cast<const float4*>(hs);
  const float4* __restrict__ g4p = reinterpret_cast<const float4*>(gw);

  float r[TOK_PER_WAVE * NEXP];
#pragma unroll
  for (int i = 0; i < TOK_PER_WAVE * NEXP; ++i) r[i] = 0.f;

#pragma unroll 2
  for (int k = 0; k < ITERS; ++k) {
    const int idx = lane + 64 * k;
    float4 g[NEXP];
#pragma unroll
    for (int e = 0; e < NEXP; ++e) g[e] = g4p[e * H4 + idx];
#pragma unroll
    for (int t = 0; t < TOK_PER_WAVE; ++t) {
      const float4 hv = h4p[(tokenBase + t) * H4 + idx];
#pragma unroll
      for (int e = 0; e < NEXP; ++e) {
        float a = r[t * NEXP + e];
        a = fmaf(hv.x, g[e].x, a);
        a = fmaf(hv.y, g[e].y, a);
        a = fmaf(hv.z, g[e].z, a);
        a = fmaf(hv.w, g[e].w, a);
        r[t * NEXP + e] = a;
      }
    }
  }

  // Reduce 32 values across 64 lanes; lane l ends holding sum of value (l>>1).
  RED_STEP(32, 16)
  RED_STEP(16, 8)
  RED_STEP(8, 4)
  RED_STEP(4, 2)
  RED_STEP(2, 1)
  float red = r[0] + __shfl_xor(r[0], 1, 64);

  // v = lane>>1 ; token t = v>>3 ; expert e = v&7
  {
    const int t = lane >> 4;
    const int e = (lane >> 1) & 7;
    if ((lane & 1) == 0) {
      out[OFF_LG + (tokenBase + t) * NEXP + e] = red;
    }
  }

  // Gather the 8 logits of this lane-group's token.
  float le[NEXP];
  const int groupBase = lane & 48;
#pragma unroll
  for (int e = 0; e < NEXP; ++e) le[e] = __shfl(red, groupBase + 2 * e, 64);

  if ((lane & 15) == 0) {
    const int tok = tokenBase + (lane >> 4);
    // top-1 (strict > => lowest index wins ties, like lax.top_k)
    int i1 = 0; float m1 = le[0];
#pragma unroll
    for (int e = 1; e < NEXP; ++e) {
      if (le[e] > m1) { m1 = le[e]; i1 = e; }
    }
    int i2 = (i1 == 0) ? 1 : 0; float m2 = le[i2];
#pragma unroll
    for (int e = 0; e < NEXP; ++e) {
      if (e != i1 && le[e] > m2) { m2 = le[e]; i2 = e; }
    }
    // full softmax (max-shifted)
    float p[NEXP];
    float psum = 0.f;
#pragma unroll
    for (int e = 0; e < NEXP; ++e) { p[e] = expf(le[e] - m1); psum += p[e]; }
    const float inv = 1.0f / psum;
#pragma unroll
    for (int e = 0; e < NEXP; ++e) atomicAdd(&smP[e], p[e] * inv);
    atomicAdd(&smC[i1], 1.0f);

    // normalized top-2 routing weights: p[i1] = 1, p[i2] = exp(m2-m1)
    const float w1 = p[i1], w2 = p[i2];
    const float rs = 1.0f / (w1 + w2);
    out[OFF_RW + tok * 2 + 0] = w1 * rs;
    out[OFF_RW + tok * 2 + 1] = w2 * rs;
    out[OFF_SE + tok * 2 + 0] = (float)i1;
    out[OFF_SE + tok * 2 + 1] = (float)i2;
  }

  __syncthreads();
  if (threadIdx.x < NEXP) {
    atomicAdd(&ws[threadIdx.x], smP[threadIdx.x]);          // sum of probs
    atomicAdd(&ws[NEXP + threadIdx.x], smC[threadIdx.x]);   // top1 counts
  }
}

__global__ void aux_kernel(const float* __restrict__ ws, float* __restrict__ out) {
  if (threadIdx.x == 0 && blockIdx.x == 0) {
    const float invT = 1.0f / (float)T_TOKENS;
    float s = 0.f;
#pragma unroll
    for (int e = 0; e < NEXP; ++e) {
      const float f = ws[NEXP + e] * invT;  // mean one-hot(top1)
      const float P = ws[e] * invT;         // mean probs
      s += f * P;
    }
    out[OFF_AUX] = 0.01f * (float)NEXP * s;
  }
}

extern "C" void kernel_launch(void* const* d_in, const int* in_sizes, int n_in,
                              void* d_out, int out_size, void* d_ws, size_t ws_size,
                              hipStream_t stream) {
  const float* hs = (const float*)d_in[0];   // (16384, 4096) f32
  const float* gw = (const float*)d_in[1];   // (8, 4096) f32
  float* out = (float*)d_out;
  float* ws  = (float*)d_ws;

  hipMemsetAsync(d_ws, 0, 2 * NEXP * sizeof(float), stream);

  const int blocks = T_TOKENS / TOK_PER_BLOCK;  // 1024
  router_kernel<<<blocks, 256, 0, stream>>>(hs, gw, out, ws);
  aux_kernel<<<1, 64, 0, stream>>>(ws, out);
}

// Round 3
// 373.135 us; speedup vs baseline: 1.0409x; 1.0409x over previous
//
#include <hip/hip_runtime.h>
#include <math.h>

// MoE router: T=16384 tokens, H=4096, E=8 experts, K=2.
// d_out layout (float32, flat, reference return order):
//   [0      , 32768 )  routing_weights  (T,2)
//   [32768  , 65536 )  selected_experts (T,2)  stored as float(index)
//   [65536  , 196608)  router_logits    (T,8)
//   [196608 ]          aux_loss (scalar)
// d_ws: 16 rows x 1024 blocks of per-block partials (plain stores, no init):
//   row e   (e=0..7):  sum of softmax probs for expert e
//   row 8+e (e=0..7):  top-1 counts for expert e

#define T_TOKENS 16384
#define H_DIM    4096
#define NEXP     8
#define H4       (H_DIM / 4)   // 1024 float4 per row
#define ITERS    (H4 / 64)     // 16 float4 chunks per lane per token
#define TOK_PER_WAVE 4
#define WAVES_PER_BLOCK 4
#define TOK_PER_BLOCK (TOK_PER_WAVE * WAVES_PER_BLOCK)  // 16
#define NBLOCKS (T_TOKENS / TOK_PER_BLOCK)              // 1024

#define OFF_RW  0
#define OFF_SE  32768
#define OFF_LG  65536
#define OFF_AUX 196608

// Native vector type usable with __builtin_nontemporal_load (HIP's float4 is
// a class and is rejected by the builtin).
typedef float vfloat4 __attribute__((ext_vector_type(4)));

// Halving butterfly step: value set of size 2N -> N, summing over lane pairs
// differing in bit OFFSET. After all steps lane l holds full sum of value l>>1.
#define RED_STEP(OFFSET, N)                                        \
  {                                                                \
    const bool hi = (lane & (OFFSET)) != 0;                        \
    _Pragma("unroll")                                              \
    for (int i = 0; i < (N); ++i) {                                \
      float send = hi ? r[i] : r[i + (N)];                         \
      float recv = __shfl_xor(send, (OFFSET), 64);                 \
      r[i] = (hi ? r[i + (N)] : r[i]) + recv;                      \
    }                                                              \
  }

__global__ __launch_bounds__(256, 4)
void router_kernel(const float* __restrict__ hs, const float* __restrict__ gw,
                   float* __restrict__ out, float* __restrict__ ws) {
  __shared__ float smP[NEXP];
  __shared__ float smC[NEXP];
  if (threadIdx.x < NEXP) { smP[threadIdx.x] = 0.f; smC[threadIdx.x] = 0.f; }
  __syncthreads();

  const int lane = threadIdx.x & 63;
  const int wave = threadIdx.x >> 6;
  const int tokenBase = (blockIdx.x * WAVES_PER_BLOCK + wave) * TOK_PER_WAVE;

  const vfloat4* __restrict__ h4p = reinterpret_cast<const vfloat4*>(hs);
  const vfloat4* __restrict__ g4p = reinterpret_cast<const vfloat4*>(gw);

  float r[TOK_PER_WAVE * NEXP];
#pragma unroll
  for (int i = 0; i < TOK_PER_WAVE * NEXP; ++i) r[i] = 0.f;

#pragma unroll 2
  for (int k = 0; k < ITERS; ++k) {
    const int idx = lane + 64 * k;
    // Hidden stream: nontemporal (read-once 256 MB) so it doesn't evict the
    // 128 KB gate matrix from L1/L2.
    vfloat4 hv[TOK_PER_WAVE];
#pragma unroll
    for (int t = 0; t < TOK_PER_WAVE; ++t)
      hv[t] = __builtin_nontemporal_load(&h4p[(tokenBase + t) * H4 + idx]);
    vfloat4 g[NEXP];
#pragma unroll
    for (int e = 0; e < NEXP; ++e) g[e] = g4p[e * H4 + idx];
#pragma unroll
    for (int t = 0; t < TOK_PER_WAVE; ++t) {
#pragma unroll
      for (int e = 0; e < NEXP; ++e) {
        float a = r[t * NEXP + e];
        a = fmaf(hv[t].x, g[e].x, a);
        a = fmaf(hv[t].y, g[e].y, a);
        a = fmaf(hv[t].z, g[e].z, a);
        a = fmaf(hv[t].w, g[e].w, a);
        r[t * NEXP + e] = a;
      }
    }
  }

  // Reduce 32 values across 64 lanes; lane l ends holding sum of value (l>>1).
  RED_STEP(32, 16)
  RED_STEP(16, 8)
  RED_STEP(8, 4)
  RED_STEP(4, 2)
  RED_STEP(2, 1)
  float red = r[0] + __shfl_xor(r[0], 1, 64);

  // v = lane>>1 ; token t = v>>3 ; expert e = v&7
  {
    const int t = lane >> 4;
    const int e = (lane >> 1) & 7;
    if ((lane & 1) == 0) {
      out[OFF_LG + (tokenBase + t) * NEXP + e] = red;
    }
  }

  // Gather the 8 logits of this lane-group's token.
  float le[NEXP];
  const int groupBase = lane & 48;
#pragma unroll
  for (int e = 0; e < NEXP; ++e) le[e] = __shfl(red, groupBase + 2 * e, 64);

  if ((lane & 15) == 0) {
    const int tok = tokenBase + (lane >> 4);
    // top-1 (strict > => lowest index wins ties, like lax.top_k)
    int i1 = 0; float m1 = le[0];
#pragma unroll
    for (int e = 1; e < NEXP; ++e) {
      if (le[e] > m1) { m1 = le[e]; i1 = e; }
    }
    int i2 = (i1 == 0) ? 1 : 0; float m2 = le[i2];
#pragma unroll
    for (int e = 0; e < NEXP; ++e) {
      if (e != i1 && le[e] > m2) { m2 = le[e]; i2 = e; }
    }
    // full softmax (max-shifted)
    float p[NEXP];
    float psum = 0.f;
#pragma unroll
    for (int e = 0; e < NEXP; ++e) { p[e] = expf(le[e] - m1); psum += p[e]; }
    const float inv = 1.0f / psum;
#pragma unroll
    for (int e = 0; e < NEXP; ++e) atomicAdd(&smP[e], p[e] * inv);
    atomicAdd(&smC[i1], 1.0f);

    // normalized top-2 routing weights: p[i1] = 1, p[i2] = exp(m2-m1)
    const float w1 = p[i1], w2 = p[i2];
    const float rs = 1.0f / (w1 + w2);
    out[OFF_RW + tok * 2 + 0] = w1 * rs;
    out[OFF_RW + tok * 2 + 1] = w2 * rs;
    out[OFF_SE + tok * 2 + 0] = (float)i1;
    out[OFF_SE + tok * 2 + 1] = (float)i2;
  }

  __syncthreads();
  // Per-block partials: row-major [16 rows][1024 blocks]; plain stores, no
  // init needed (d_ws is poison — we overwrite every slot we later read).
  if (threadIdx.x < 2 * NEXP) {
    const float v = (threadIdx.x < NEXP) ? smP[threadIdx.x]
                                         : smC[threadIdx.x - NEXP];
    ws[threadIdx.x * NBLOCKS + blockIdx.x] = v;
  }
}

__global__ __launch_bounds__(1024)
void aux_kernel(const float* __restrict__ ws, float* __restrict__ out) {
  __shared__ float sm[2 * NEXP];
  const int lane = threadIdx.x & 63;
  const int w = threadIdx.x >> 6;  // 16 waves, one per partial row
  float s = 0.f;
#pragma unroll
  for (int i = 0; i < NBLOCKS / 64; ++i) s += ws[w * NBLOCKS + lane + 64 * i];
#pragma unroll
  for (int off = 32; off > 0; off >>= 1) s += __shfl_xor(s, off, 64);
  if (lane == 0) sm[w] = s;
  __syncthreads();
  if (threadIdx.x == 0) {
    const float invT = 1.0f / (float)T_TOKENS;
    float acc = 0.f;
#pragma unroll
    for (int e = 0; e < NEXP; ++e) {
      const float f = sm[NEXP + e] * invT;  // mean one-hot(top1)
      const float P = sm[e] * invT;         // mean probs
      acc += f * P;
    }
    out[OFF_AUX] = 0.01f * (float)NEXP * acc;
  }
}

extern "C" void kernel_launch(void* const* d_in, const int* in_sizes, int n_in,
                              void* d_out, int out_size, void* d_ws, size_t ws_size,
                              hipStream_t stream) {
  const float* hs = (const float*)d_in[0];   // (16384, 4096) f32
  const float* gw = (const float*)d_in[1];   // (8, 4096) f32
  float* out = (float*)d_out;
  float* ws  = (float*)d_ws;

  router_kernel<<<NBLOCKS, 256, 0, stream>>>(hs, gw, out, ws);
  aux_kernel<<<1, 1024, 0, stream>>>(ws, out);
}

// Round 4
// 353.959 us; speedup vs baseline: 1.0973x; 1.0542x over previous
//
#include <hip/hip_runtime.h>
#include <math.h>

// MoE router: T=16384 tokens, H=4096, E=8 experts, K=2.
// d_out layout (float32, flat, reference return order):
//   [0      , 32768 )  routing_weights  (T,2)
//   [32768  , 65536 )  selected_experts (T,2)  stored as float(index)
//   [65536  , 196608)  router_logits    (T,8)
//   [196608 ]          aux_loss (scalar)
// d_ws: 16 rows x NBLOCKS of per-block partials (plain stores, no init):
//   row e   (e=0..7):  sum of softmax probs for expert e
//   row 8+e (e=0..7):  top-1 counts for expert e

#define T_TOKENS 16384
#define H_DIM    4096
#define NEXP     8
#define H4       (H_DIM / 4)   // 1024 float4 per row
#define ITERS    (H4 / 64)     // 16 float4 chunks per lane per token
#define TOK_PER_WAVE 8
#define WAVES_PER_BLOCK 4
#define TOK_PER_BLOCK (TOK_PER_WAVE * WAVES_PER_BLOCK)  // 32
#define NBLOCKS (T_TOKENS / TOK_PER_BLOCK)              // 512

#define OFF_RW  0
#define OFF_SE  32768
#define OFF_LG  65536
#define OFF_AUX 196608

// Native vector type usable with __builtin_nontemporal_load (HIP's float4 is
// a class and is rejected by the builtin).
typedef float vfloat4 __attribute__((ext_vector_type(4)));

// Halving butterfly step: value set of size 2N -> N, summing over lane pairs
// differing in bit OFFSET. Starting from 64 values r[0..63], after steps
// OFFSET=32,16,8,4,2,1 lane l holds the full 64-lane sum of value l.
#define RED_STEP(OFFSET, N)                                        \
  {                                                                \
    const bool hi = (lane & (OFFSET)) != 0;                        \
    _Pragma("unroll")                                              \
    for (int i = 0; i < (N); ++i) {                                \
      float send = hi ? r[i] : r[i + (N)];                         \
      float recv = __shfl_xor(send, (OFFSET), 64);                 \
      r[i] = (hi ? r[i + (N)] : r[i]) + recv;                      \
    }                                                              \
  }

__global__ __launch_bounds__(256, 2)
void router_kernel(const float* __restrict__ hs, const float* __restrict__ gw,
                   float* __restrict__ out, float* __restrict__ ws) {
  __shared__ float smP[NEXP];
  __shared__ float smC[NEXP];
  if (threadIdx.x < NEXP) { smP[threadIdx.x] = 0.f; smC[threadIdx.x] = 0.f; }
  __syncthreads();

  const int lane = threadIdx.x & 63;
  const int wave = threadIdx.x >> 6;
  const int tokenBase = (blockIdx.x * WAVES_PER_BLOCK + wave) * TOK_PER_WAVE;

  const vfloat4* __restrict__ h4p = reinterpret_cast<const vfloat4*>(hs);
  const vfloat4* __restrict__ g4p = reinterpret_cast<const vfloat4*>(gw);

  float r[TOK_PER_WAVE * NEXP];  // 64 accumulators: r[t*8+e]
#pragma unroll
  for (int i = 0; i < TOK_PER_WAVE * NEXP; ++i) r[i] = 0.f;

  for (int k = 0; k < ITERS; ++k) {
    const int idx = lane + 64 * k;
    // Hidden stream: nontemporal (read-once 256 MB) so it doesn't evict the
    // 128 KB gate matrix from L2.
    vfloat4 hv[TOK_PER_WAVE];
#pragma unroll
    for (int t = 0; t < TOK_PER_WAVE; ++t)
      hv[t] = __builtin_nontemporal_load(&h4p[(tokenBase + t) * H4 + idx]);
    vfloat4 g[NEXP];
#pragma unroll
    for (int e = 0; e < NEXP; ++e) g[e] = g4p[e * H4 + idx];
#pragma unroll
    for (int t = 0; t < TOK_PER_WAVE; ++t) {
#pragma unroll
      for (int e = 0; e < NEXP; ++e) {
        float a = r[t * NEXP + e];
        a = fmaf(hv[t].x, g[e].x, a);
        a = fmaf(hv[t].y, g[e].y, a);
        a = fmaf(hv[t].z, g[e].z, a);
        a = fmaf(hv[t].w, g[e].w, a);
        r[t * NEXP + e] = a;
      }
    }
  }

  // Perfect 64-value butterfly: lane l ends holding full sum of value l
  // (token = l>>3, expert = l&7).
  RED_STEP(32, 32)
  RED_STEP(16, 16)
  RED_STEP(8, 8)
  RED_STEP(4, 4)
  RED_STEP(2, 2)
  float red;
  {
    const bool hi = (lane & 1) != 0;
    float send = hi ? r[0] : r[1];
    float recv = __shfl_xor(send, 1, 64);
    red = (hi ? r[1] : r[0]) + recv;
  }

  // All 64 lanes store one logit each: 256 B contiguous per wave.
  out[OFF_LG + tokenBase * NEXP + lane] = red;

  // Gather the 8 logits of this lane-group's token.
  float le[NEXP];
  const int groupBase = lane & 56;
#pragma unroll
  for (int e = 0; e < NEXP; ++e) le[e] = __shfl(red, groupBase + e, 64);

  if ((lane & 7) == 0) {
    const int tok = tokenBase + (lane >> 3);
    // top-1 (strict > => lowest index wins ties, like lax.top_k)
    int i1 = 0; float m1 = le[0];
#pragma unroll
    for (int e = 1; e < NEXP; ++e) {
      if (le[e] > m1) { m1 = le[e]; i1 = e; }
    }
    int i2 = (i1 == 0) ? 1 : 0; float m2 = le[i2];
#pragma unroll
    for (int e = 0; e < NEXP; ++e) {
      if (e != i1 && le[e] > m2) { m2 = le[e]; i2 = e; }
    }
    // full softmax (max-shifted)
    float p[NEXP];
    float psum = 0.f;
#pragma unroll
    for (int e = 0; e < NEXP; ++e) { p[e] = expf(le[e] - m1); psum += p[e]; }
    const float inv = 1.0f / psum;
#pragma unroll
    for (int e = 0; e < NEXP; ++e) atomicAdd(&smP[e], p[e] * inv);
    atomicAdd(&smC[i1], 1.0f);

    // normalized top-2 routing weights: p[i1] = 1, p[i2] = exp(m2-m1)
    const float w1 = p[i1], w2 = p[i2];
    const float rs = 1.0f / (w1 + w2);
    out[OFF_RW + tok * 2 + 0] = w1 * rs;
    out[OFF_RW + tok * 2 + 1] = w2 * rs;
    out[OFF_SE + tok * 2 + 0] = (float)i1;
    out[OFF_SE + tok * 2 + 1] = (float)i2;
  }

  __syncthreads();
  // Per-block partials: row-major [16 rows][NBLOCKS]; plain stores, no
  // init needed (d_ws is poison — we overwrite every slot we later read).
  if (threadIdx.x < 2 * NEXP) {
    const float v = (threadIdx.x < NEXP) ? smP[threadIdx.x]
                                         : smC[threadIdx.x - NEXP];
    ws[threadIdx.x * NBLOCKS + blockIdx.x] = v;
  }
}

__global__ __launch_bounds__(1024)
void aux_kernel(const float* __restrict__ ws, float* __restrict__ out) {
  __shared__ float sm[2 * NEXP];
  const int lane = threadIdx.x & 63;
  const int w = threadIdx.x >> 6;  // 16 waves, one per partial row
  float s = 0.f;
#pragma unroll
  for (int i = 0; i < NBLOCKS / 64; ++i) s += ws[w * NBLOCKS + lane + 64 * i];
#pragma unroll
  for (int off = 32; off > 0; off >>= 1) s += __shfl_xor(s, off, 64);
  if (lane == 0) sm[w] = s;
  __syncthreads();
  if (threadIdx.x == 0) {
    const float invT = 1.0f / (float)T_TOKENS;
    float acc = 0.f;
#pragma unroll
    for (int e = 0; e < NEXP; ++e) {
      const float f = sm[NEXP + e] * invT;  // mean one-hot(top1)
      const float P = sm[e] * invT;         // mean probs
      acc += f * P;
    }
    out[OFF_AUX] = 0.01f * (float)NEXP * acc;
  }
}

extern "C" void kernel_launch(void* const* d_in, const int* in_sizes, int n_in,
                              void* d_out, int out_size, void* d_ws, size_t ws_size,
                              hipStream_t stream) {
  const float* hs = (const float*)d_in[0];   // (16384, 4096) f32
  const float* gw = (const float*)d_in[1];   // (8, 4096) f32
  float* out = (float*)d_out;
  float* ws  = (float*)d_ws;

  router_kernel<<<NBLOCKS, 256, 0, stream>>>(hs, gw, out, ws);
  aux_kernel<<<1, 1024, 0, stream>>>(ws, out);
}